// Round 3
// baseline (51.821 us; speedup 1.0000x reference)
//
#include <hip/hip_runtime.h>
#include <hip/hip_bf16.h>

// SCC: out[b,o,h,w] = sum_{j=0..7} w[o,j] * x[b, (o*4 + j) % 64, h, w]
// B=32, C_IN=C_OUT=64, H=W=128, G=8, STEP=4. All float32.
//
// Round 3: float4 traffic (16 B/lane) AND full occupancy. Split the 16
// sliding-window base positions into 4 quarters across threads:
//   thread quarter q0 = tid>>6 handles window positions wi=4q0..4q0+3,
//   i.e. 16 output channels o = 4q0 + wi' + 16q, reading input channels
//   16q0 .. 16q0+19 (mod 64).
// The 4-channel overlap between adjacent quarters is re-read by threads
// of the SAME block close in time -> L1/L2 hit, not HBM. Grid = 2048
// blocks = 8192 waves = 32 waves/CU (vs 512 blocks / 8 waves/CU in R2).
// q0 is wave-uniform: weight LDS reads broadcast, stores stay coalesced.

#define CIN   64
#define COUT  64
#define GW    8
#define HW4   4096            // (128*128)/4 float4-pixels per channel plane

__global__ __launch_bounds__(256) void scc_kernel(
    const float4* __restrict__ x,
    const float*  __restrict__ w,
    float4* __restrict__ out)
{
    __shared__ float ws[COUT * GW];           // 2 KB
    for (int i = threadIdx.x; i < COUT * GW; i += blockDim.x)
        ws[i] = w[i];
    __syncthreads();

    const int tid = threadIdx.x;
    const int q0  = tid >> 6;                 // wave-uniform quarter 0..3
    const int pi  = blockIdx.x * 64 + (tid & 63);  // float4-pixel id
    const int b   = pi >> 12;                 // / 4096
    const int hw4 = pi & (HW4 - 1);

    const float4* xp = x   + ((long)b * CIN) * HW4 + hw4;
    float4*       op = out + ((long)b * COUT) * HW4 + hw4;

    const int cbase = 16 * q0;                // first channel of this quarter

    // Prime the window: channels cbase .. cbase+7 (mod 64).
    float4 win[8];
#pragma unroll
    for (int k = 0; k < 8; ++k)
        win[k] = xp[(long)((cbase + k) & (CIN - 1)) * HW4];

#pragma unroll
    for (int wi = 0; wi < 4; ++wi) {
        // Prefetch the next 4 channels (window slides by 4).
        float4 nxt[4];
        if (wi < 3) {
#pragma unroll
            for (int k = 0; k < 4; ++k)
                nxt[k] = xp[(long)((cbase + 4 * wi + 8 + k) & (CIN - 1)) * HW4];
        }

        // 4 outputs share this window: o = 4*q0 + wi + 16*q.
#pragma unroll
        for (int q = 0; q < 4; ++q) {
            int o = 4 * q0 + wi + 16 * q;
            float4 a;
            a.x = 0.f; a.y = 0.f; a.z = 0.f; a.w = 0.f;
#pragma unroll
            for (int j = 0; j < 8; ++j) {
                float wt  = ws[o * GW + j];           // wave-uniform -> broadcast
                float4 xv = win[(4 * wi + j) & 7];    // static index
                a.x = fmaf(wt, xv.x, a.x);
                a.y = fmaf(wt, xv.y, a.y);
                a.z = fmaf(wt, xv.z, a.z);
                a.w = fmaf(wt, xv.w, a.w);
            }
            op[(long)o * HW4] = a;
        }

        // Rotate prefetched channels into the window (static slots).
        if (wi < 3) {
#pragma unroll
            for (int k = 0; k < 4; ++k)
                win[(4 * wi + 8 + k) & 7] = nxt[k];
        }
    }
}

extern "C" void kernel_launch(void* const* d_in, const int* in_sizes, int n_in,
                              void* d_out, int out_size, void* d_ws, size_t ws_size,
                              hipStream_t stream) {
    const float4* x = (const float4*)d_in[0];
    const float*  w = (const float*)d_in[1];
    float4* out     = (float4*)d_out;

    // 131072 float4-pixels, 64 pixels per block (x4 quarters = 256 threads)
    const int block = 256;
    const int grid  = 131072 / 64;            // 2048 blocks

    scc_kernel<<<grid, block, 0, stream>>>(x, w, out);
}

// Round 4
// 48.528 us; speedup vs baseline: 1.0678x; 1.0678x over previous
//
#include <hip/hip_runtime.h>
#include <hip/hip_bf16.h>

// SCC: out[b,o,h,w] = sum_{j=0..7} w[o,j] * x[b, (o*4 + j) % 64, h, w]
// B=32, C_IN=C_OUT=64, H=W=128, G=8, STEP=4. All float32.
//
// Round 4: float2 per thread (8 B/lane — the coalescing sweet spot),
// full 16-position sliding window per thread => ZERO redundant traffic
// (R3 showed redundant loads cost linearly at the vmem-byte wall), and
// 262144 threads = 1024 blocks = 16 waves/CU (R2's 8 waves/CU at float4
// couldn't hide latency). Weights are read directly with uniform
// compile-time indices -> compiler scalarizes to s_load on the idle
// SMEM pipe (no LDS, no __syncthreads, no lgkm contention).

#define CIN   64
#define COUT  64
#define GW    8
#define HW2   8192            // (128*128)/2 float2-pixels per channel plane

__global__ __launch_bounds__(256) void scc_kernel(
    const float2* __restrict__ x,
    const float*  __restrict__ w,
    float2* __restrict__ out)
{
    const int t   = blockIdx.x * blockDim.x + threadIdx.x;  // float2-pixel id
    const int b   = t >> 13;                                 // / 8192
    const int hw2 = t & (HW2 - 1);

    const float2* xp = x   + ((long)b * CIN) * HW2 + hw2;
    float2*       op = out + ((long)b * COUT) * HW2 + hw2;

    // Prime the window with channels 0..7.
    float2 win[8];
#pragma unroll
    for (int k = 0; k < 8; ++k)
        win[k] = xp[(long)k * HW2];

#pragma unroll
    for (int wi = 0; wi < 16; ++wi) {
        // Prefetch the next 4 channels (window slides by 4).
        float2 nxt[4];
        if (wi < 15) {
#pragma unroll
            for (int k = 0; k < 4; ++k)
                nxt[k] = xp[(long)((4 * wi + 8 + k) & (CIN - 1)) * HW2];
        }

        // 4 outputs share this window: o = wi + 16*q.
#pragma unroll
        for (int q = 0; q < 4; ++q) {
            const int o = wi + 16 * q;
            float ax = 0.f, ay = 0.f;
#pragma unroll
            for (int j = 0; j < 8; ++j) {
                float  wt = w[o * GW + j];           // uniform -> s_load
                float2 xv = win[(4 * wi + j) & 7];   // static index
                ax = fmaf(wt, xv.x, ax);
                ay = fmaf(wt, xv.y, ay);
            }
            float2 a; a.x = ax; a.y = ay;
            op[(long)o * HW2] = a;
        }

        // Rotate prefetched channels into the window (static slots).
        if (wi < 15) {
#pragma unroll
            for (int k = 0; k < 4; ++k)
                win[(4 * wi + 8 + k) & 7] = nxt[k];
        }
    }
}

extern "C" void kernel_launch(void* const* d_in, const int* in_sizes, int n_in,
                              void* d_out, int out_size, void* d_ws, size_t ws_size,
                              hipStream_t stream) {
    const float2* x = (const float2*)d_in[0];
    const float*  w = (const float*)d_in[1];
    float2* out     = (float2*)d_out;

    const int total = 32 * HW2;               // 262144 float2-pixels
    const int block = 256;
    const int grid  = total / block;          // 1024 blocks

    scc_kernel<<<grid, block, 0, stream>>>(x, w, out);
}

// Round 5
// 45.966 us; speedup vs baseline: 1.1274x; 1.0557x over previous
//
#include <hip/hip_runtime.h>
#include <hip/hip_bf16.h>

// SCC: out[b,o,h,w] = sum_{j=0..7} w[o,j] * x[b, (o*4 + j) % 64, h, w]
// B=32, C_IN=C_OUT=64, H=W=128, G=8, STEP=4. All float32.
//
// Round 5: exact R1 structure (scalar pixel-per-thread, 8192 waves =
// every wave slot on the chip, zero redundant traffic — the best point
// found in the width/occupancy/redundancy space) with ONE change:
// non-temporal stores. R1..R4 counters show the output stream evicts
// half of x from the 256 MiB L3 between replays (FETCH_SIZE == x/2).
// `nt` stores mark output lines evict-first, so x stays L3-resident,
// reads ride the cache, and HBM carries only the compulsory writes.

#define CIN   64
#define COUT  64
#define GW    8
#define STEP  4
#define HW    (128 * 128)

__global__ __launch_bounds__(256) void scc_kernel(
    const float* __restrict__ x,
    const float* __restrict__ w,
    float* __restrict__ out,
    int total_pixels)
{
    __shared__ float ws[COUT * GW];
    for (int i = threadIdx.x; i < COUT * GW; i += blockDim.x)
        ws[i] = w[i];
    __syncthreads();

    int p = blockIdx.x * blockDim.x + threadIdx.x;   // pixel id in [0, B*HW)
    if (p >= total_pixels) return;

    int b  = p >> 14;          // p / HW   (HW = 16384 = 2^14)
    int hw = p & (HW - 1);     // p % HW

    const float* xp = x + ((long)b * CIN) * HW + hw;
    float* op       = out + ((long)b * COUT) * HW + hw;

    // Load all 64 channels for this pixel into registers.
    float xv[CIN];
#pragma unroll
    for (int c = 0; c < CIN; ++c)
        xv[c] = xp[(long)c * HW];

    // Compute all 64 output channels; indices are compile-time constants.
#pragma unroll
    for (int o = 0; o < COUT; ++o) {
        float acc = 0.0f;
#pragma unroll
        for (int j = 0; j < GW; ++j)
            acc = fmaf(ws[o * GW + j], xv[(o * STEP + j) & (CIN - 1)], acc);
        __builtin_nontemporal_store(acc, &op[(long)o * HW]);
    }
}

extern "C" void kernel_launch(void* const* d_in, const int* in_sizes, int n_in,
                              void* d_out, int out_size, void* d_ws, size_t ws_size,
                              hipStream_t stream) {
    const float* x = (const float*)d_in[0];
    const float* w = (const float*)d_in[1];
    float* out     = (float*)d_out;

    const int total_pixels = 32 * HW;   // B * H * W = 524288
    const int block = 256;
    const int grid  = (total_pixels + block - 1) / block;   // 2048

    scc_kernel<<<grid, block, 0, stream>>>(x, w, out, total_pixels);
}